// Round 8
// baseline (79.216 us; speedup 1.0000x reference)
//
#include <hip/hip_runtime.h>
#include <hip/hip_bf16.h>

typedef unsigned short u16;
typedef short s16x8 __attribute__((ext_vector_type(8)));
typedef u16 u16x8 __attribute__((ext_vector_type(8)));
typedef unsigned int u32x4 __attribute__((ext_vector_type(4)));
typedef float f32x4 __attribute__((ext_vector_type(4)));

struct cplx { float x, y; };

#define L_SEQ 2048
#define HID 512
#define NST 64

// ---------------- device scratch (fully rewritten every call) ----------------
__device__ __align__(16) cplx g_khat[L_SEQ];        // k̂_j at 2048 roots of unity
__device__ __align__(16) u16 g_Td[32 * 64 * 64];    // bf16 diagonal tiles: Td[d][r][c]=k[64d+r-c]
__device__ __align__(16) u16 g_Xt[HID * L_SEQ];     // bf16 X^T  [h][l]
__device__ __align__(16) u16 g_W1[HID * HID];       // bf16 [n][k]
__device__ __align__(16) u16 g_W2[HID * HID];
__device__ __align__(16) u16 g_H[L_SEQ * HID];      // bf16 gelu(conv out) [l][h]

__device__ __forceinline__ u16 f2bf(float f) {
    union { __hip_bfloat16 h; u16 u; } cv;
    cv.h = __float2bfloat16(f);
    return cv.u;
}

// ---------------- fused: X transpose + W converts + khat ----------------
// blocks 0..255: X -> bf16 X^T ; 256..767: W1/W2 ; 768..775: khat
// k̂_j = 2 conj(C)^T [ (2/Δ)(1-ω)I - (1+ω)A ]^{-1} B ; A = diag(Λ) - P P^H (Woodbury)
__global__ __launch_bounds__(256) void fused_convert(
    const float* x, const float* w1, const float* w2,
    const float* lre, const float* lim, const float* pre, const float* pim,
    const float* bre, const float* bim, const float* cre, const float* cim,
    const float* lstep) {
    __shared__ float tile[64][65];
    __shared__ float sLre[NST], sLim[NST], sPre[NST], sPim[NST];
    __shared__ float sBre[NST], sBim[NST], sCre[NST], sCim[NST];
    int b = blockIdx.x, tid = threadIdx.x;
    if (b < 256) {
        int lt = b >> 3, ht = b & 7;
#pragma unroll
        for (int i = 0; i < 4; i++) {
            int idx = i * 256 + tid;        // 1024 float4
            int r = idx >> 4, c4 = idx & 15;
            f32x4 v = *(const f32x4*)&x[(lt * 64 + r) * HID + ht * 64 + c4 * 4];
            tile[r][c4 * 4 + 0] = v.x;
            tile[r][c4 * 4 + 1] = v.y;
            tile[r][c4 * 4 + 2] = v.z;
            tile[r][c4 * 4 + 3] = v.w;
        }
        __syncthreads();
#pragma unroll
        for (int i = 0; i < 2; i++) {
            int idx = i * 256 + tid;        // 512 u16x8
            int rr = idx >> 3, c8 = idx & 7;
            u16x8 v;
#pragma unroll
            for (int q = 0; q < 8; q++) v[q] = f2bf(tile[c8 * 8 + q][rr]);
            *(u16x8*)&g_Xt[(ht * 64 + rr) * L_SEQ + lt * 64 + c8 * 8] = v;
        }
    } else if (b < 768) {
        int t = (b - 256) * 256 + tid;  // 131072
        const float* src = (t < 65536) ? w1 : w2;
        u16* dst = (t < 65536) ? g_W1 : g_W2;
        int idx = (t < 65536) ? t : (t - 65536);
        float4 v = ((const float4*)src)[idx];
        unsigned long long pk = (unsigned long long)f2bf(v.x) |
                                ((unsigned long long)f2bf(v.y) << 16) |
                                ((unsigned long long)f2bf(v.z) << 32) |
                                ((unsigned long long)f2bf(v.w) << 48);
        ((unsigned long long*)dst)[idx] = pk;
    } else {
        if (tid < NST) {
            sLre[tid] = lre[tid]; sLim[tid] = lim[tid];
            sPre[tid] = pre[tid]; sPim[tid] = pim[tid];
            sBre[tid] = bre[tid]; sBim[tid] = bim[tid];
            sCre[tid] = cre[tid]; sCim[tid] = cim[tid];
        }
        __syncthreads();
        int j = (b - 768) * 256 + tid;  // 0..2047
        float tdt = 2.0f * __expf(-lstep[0]);          // 2/step
        float th = 0.00306796157577128245f * j;        // 2*pi/2048 * j
        float sn, cs;
        __sincosf(th, &sn, &cs);
        float aRe = tdt * (1.f - cs), aIm = tdt * sn;  // (2/dt)(1-w)
        float bRe = 1.f + cs, bIm = -sn;               // beta = 1+w
        float cBx = 0.f, cBy = 0.f, cPx = 0.f, cPy = 0.f;
        float pBx = 0.f, pBy = 0.f, pPx = 0.f, pPy = 0.f;
#pragma unroll 8
        for (int n = 0; n < NST; n++) {
            float Lre = sLre[n], Lim = sLim[n];
            float Dre = aRe - (bRe * Lre - bIm * Lim);
            float Dim = aIm - (bRe * Lim + bIm * Lre);
            float inv = 1.f / (Dre * Dre + Dim * Dim);
            float eRe = Dre * inv, eIm = -Dim * inv;   // 1/D_n
            float cRe = sCre[n], cIm = -sCim[n];
            float t1Re = cRe * eRe - cIm * eIm, t1Im = cRe * eIm + cIm * eRe;
            float qRe = sPre[n], qIm = -sPim[n];
            float t2Re = qRe * eRe - qIm * eIm, t2Im = qRe * eIm + qIm * eRe;
            float BRe = sBre[n], BIm = sBim[n], PRe = sPre[n], PIm = sPim[n];
            cBx += t1Re * BRe - t1Im * BIm; cBy += t1Re * BIm + t1Im * BRe;
            cPx += t1Re * PRe - t1Im * PIm; cPy += t1Re * PIm + t1Im * PRe;
            pBx += t2Re * BRe - t2Im * BIm; pBy += t2Re * BIm + t2Im * BRe;
            pPx += t2Re * PRe - t2Im * PIm; pPy += t2Re * PIm + t2Im * PRe;
        }
        float denx = 1.f + (bRe * pPx - bIm * pPy);
        float deny = (bRe * pPy + bIm * pPx);
        float bcPx = bRe * cPx - bIm * cPy;
        float bcPy = bRe * cPy + bIm * cPx;
        float numx = bcPx * pBx - bcPy * pBy;
        float numy = bcPx * pBy + bcPy * pBx;
        float dinv = 1.f / (denx * denx + deny * deny);
        float corx = (numx * denx + numy * deny) * dinv;
        float cory = (numy * denx - numx * deny) * dinv;
        g_khat[j] = { 2.f * (cBx - corx), 2.f * (cBy - cory) };
    }
}

// ---------------- k_build: per-tile Hermitian IDFT + Td tile write ----------------
// block d computes k[64d-63 .. 64d+63] (127 values) and writes Td[d][r][c]=k[64d+r-c]
__global__ __launch_bounds__(1024) void k_build() {
    __shared__ float kL[128];
    int d = blockIdx.x, tid = threadIdx.x;
    int v = tid >> 3, g = tid & 7;       // value v (0..127), 8 lanes per value
    int tIdx = 64 * d - 63 + v;          // k index this group computes
    float acc = 0.f;
    if (tIdx >= 0) {
#pragma unroll 8
        for (int i = 0; i < 128; i++) {
            int j = g + 8 * i;  // 0..1023
            cplx a = g_khat[j];
            cplx b = g_khat[(2048 - j) & 2047];
            float re = 0.5f * (a.x + b.x);
            float im = 0.5f * (a.y - b.y);
            int idx = (j * tIdx) & 2047;
            float s, c;
            __sincosf(0.00306796157577128245f * idx, &s, &c);
            float wgt = (j == 0) ? 1.f : 2.f;
            acc += wgt * (re * c - im * s);
        }
    }
    acc += __shfl_xor(acc, 1);
    acc += __shfl_xor(acc, 2);
    acc += __shfl_xor(acc, 4);
    if (g == 0) {
        if (tIdx >= 0) acc += (1 - 2 * (tIdx & 1)) * g_khat[1024].x;
        kL[v] = acc * (1.f / 2048.f);
    }
    __syncthreads();
    if (tid < 512) {
        int o = tid * 8;                 // element offset in the 4096-el tile
        int r = o >> 6, c0 = o & 63;
        u16x8 vv;
#pragma unroll
        for (int q = 0; q < 8; q++) {
            int gidx = 64 * d + r - c0 - q;     // global k index
            int loc = 63 + r - c0 - q;          // kL index
            vv[q] = (gidx >= 0) ? f2bf(kL[loc]) : (u16)0;
        }
        *(u16x8*)&g_Td[d * 4096 + o] = vv;
    }
}

// ---------------- conv GEMM: Y = T @ X, BK=128, A from L2-resident Td ----------------
__global__ __launch_bounds__(256) void conv_gemm() {
    __shared__ __align__(16) u16 As[64 * 128];
    __shared__ __align__(16) u16 Bs[64 * 128];
    int tid = threadIdx.x, l = tid & 63, w = tid >> 6;
    int wm = w >> 1, wn = w & 1;
    int bm = blockIdx.x >> 3, bn = blockIdx.x & 7;  // 32 x 8
    f32x4 acc[2][2] = {};
    int nst = (bm >> 1) + 1;            // BK=128 steps (covers kb = 2s, 2s+1)
    int row0 = tid >> 3, kc0 = tid & 7;
    int row1 = row0 + 32;
    // swizzled u32x4 store slots (chunk space 16 wide, chunk = c*8 + kc)
    int st00 = row0 * 16 + ((kc0) ^ (row0 & 7));       // c=0, row0
    int st01 = row0 * 16 + ((8 + kc0) ^ (row0 & 7));   // c=1, row0
    int st10 = row1 * 16 + ((kc0) ^ (row1 & 7));
    int st11 = row1 * 16 + ((8 + kc0) ^ (row1 & 7));
    const u32x4 zz = { 0, 0, 0, 0 };

#define LOADA(D00, D10, D01, D11, S)                                         \
    {                                                                        \
        int d0_ = bm - 2 * (S), d1_ = d0_ - 1;                               \
        if (d0_ >= 0) {                                                      \
            D00 = *(const u32x4*)&g_Td[d0_ * 4096 + row0 * 64 + kc0 * 8];    \
            D10 = *(const u32x4*)&g_Td[d0_ * 4096 + row1 * 64 + kc0 * 8];    \
        } else { D00 = zz; D10 = zz; }                                       \
        if (d1_ >= 0) {                                                      \
            D01 = *(const u32x4*)&g_Td[d1_ * 4096 + row0 * 64 + kc0 * 8];    \
            D11 = *(const u32x4*)&g_Td[d1_ * 4096 + row1 * 64 + kc0 * 8];    \
        } else { D01 = zz; D11 = zz; }                                       \
    }
#define LOADB(D00, D10, D01, D11, S)                                         \
    {                                                                        \
        int k0_ = (S) * 128;                                                 \
        D00 = *(const u32x4*)&g_Xt[(bn * 64 + row0) * L_SEQ + k0_ + kc0 * 8];        \
        D10 = *(const u32x4*)&g_Xt[(bn * 64 + row1) * L_SEQ + k0_ + kc0 * 8];        \
        D01 = *(const u32x4*)&g_Xt[(bn * 64 + row0) * L_SEQ + k0_ + 64 + kc0 * 8];   \
        D11 = *(const u32x4*)&g_Xt[(bn * 64 + row1) * L_SEQ + k0_ + 64 + kc0 * 8];   \
    }

#define CONV_COMPUTE                                                         \
    _Pragma("unroll")                                                        \
    for (int ks = 0; ks < 4; ks++) {                                         \
        s16x8 af[2], bf[2];                                                  \
        _Pragma("unroll")                                                    \
        for (int m = 0; m < 2; m++) {                                        \
            int row = wm * 32 + m * 16 + (l & 15);                           \
            int ch = (ks * 4 + (l >> 4)) ^ (row & 7);                        \
            af[m] = *(const s16x8*)&As[row * 128 + ch * 8];                  \
        }                                                                    \
        _Pragma("unroll")                                                    \
        for (int n = 0; n < 2; n++) {                                        \
            int col = wn * 32 + n * 16 + (l & 15);                           \
            int ch = (ks * 4 + (l >> 4)) ^ (col & 7);                        \
            bf[n] = *(const s16x8*)&Bs[col * 128 + ch * 8];                  \
        }                                                                    \
        _Pragma("unroll")                                                    \
        for (int m = 0; m < 2; m++)                                          \
            _Pragma("unroll")                                                \
            for (int n = 0; n < 2; n++)                                      \
                acc[m][n] = __builtin_amdgcn_mfma_f32_16x16x32_bf16(         \
                    af[m], bf[n], acc[m][n], 0, 0, 0);                       \
    }

#define CONV_STEP(A00, A10, A01, A11, B00, B10, B01, B11)                    \
    {                                                                        \
        __syncthreads();                                                     \
        ((u32x4*)As)[st00] = A00; ((u32x4*)As)[st10] = A10;                  \
        ((u32x4*)As)[st01] = A01; ((u32x4*)As)[st11] = A11;                  \
        ((u32x4*)Bs)[st00] = B00; ((u32x4*)Bs)[st10] = B10;                  \
        ((u32x4*)Bs)[st01] = B01; ((u32x4*)Bs)[st11] = B11;                  \
        if (s + 2 < nst) {                                                   \
            LOADA(A00, A10, A01, A11, s + 2);                                \
            LOADB(B00, B10, B01, B11, s + 2);                                \
        }                                                                    \
        __syncthreads();                                                     \
        CONV_COMPUTE;                                                        \
        s++;                                                                 \
    }

    u32x4 aA00, aA10, aA01, aA11, bA00, bA10, bA01, bA11;
    u32x4 aB00, aB10, aB01, aB11, bB00, bB10, bB01, bB11;
    LOADA(aA00, aA10, aA01, aA11, 0);
    LOADB(bA00, bA10, bA01, bA11, 0);
    int sp = (nst > 1) ? 1 : 0;
    LOADA(aB00, aB10, aB01, aB11, sp);
    LOADB(bB00, bB10, bB01, bB11, sp);
    int s = 0;
    while (true) {
        CONV_STEP(aA00, aA10, aA01, aA11, bA00, bA10, bA01, bA11);
        if (s >= nst) break;
        CONV_STEP(aB00, aB10, aB01, aB11, bB00, bB10, bB01, bB11);
        if (s >= nst) break;
    }
#undef CONV_STEP
#undef CONV_COMPUTE
#undef LOADA
#undef LOADB
#pragma unroll
    for (int m = 0; m < 2; m++)
#pragma unroll
        for (int n = 0; n < 2; n++)
#pragma unroll
            for (int r4 = 0; r4 < 4; r4++) {
                int row = bm * 64 + wm * 32 + m * 16 + (l >> 4) * 4 + r4;
                int col = bn * 64 + wn * 32 + n * 16 + (l & 15);
                float y = acc[m][n][r4];
                float u = 1.5957691216057308f * (y + 0.044715f * y * y * y);
                float th = 1.f - 2.f / (__expf(u) + 1.f);
                g_H[row * HID + col] = f2bf(0.5f * y * (1.f + th));
            }
}

// ---------------- FFN: out = x + (H@W1^T + b1) * sigmoid(H@W2^T + b2), BK=128 ----------------
__global__ __launch_bounds__(256) void ffn_gemm(const float* x, const float* b1,
                                                const float* b2, float* out) {
    __shared__ __align__(16) u16 As[64 * 128];
    __shared__ __align__(16) u16 B1s[64 * 128];
    __shared__ __align__(16) u16 B2s[64 * 128];
    int tid = threadIdx.x, l = tid & 63, w = tid >> 6;
    int wm = w >> 1, wn = w & 1;
    int bm = blockIdx.x >> 3, bn = blockIdx.x & 7;  // 32 x 8
    f32x4 acc1[2][2] = {}, acc2[2][2] = {};
    int row0 = tid >> 3, kc0 = tid & 7;
    int row1 = row0 + 32;
    int st00 = row0 * 16 + ((kc0) ^ (row0 & 7));
    int st01 = row0 * 16 + ((8 + kc0) ^ (row0 & 7));
    int st10 = row1 * 16 + ((kc0) ^ (row1 & 7));
    int st11 = row1 * 16 + ((8 + kc0) ^ (row1 & 7));
    const u16* aB = &g_H[(bm * 64) * HID];
    const u16* w1B = &g_W1[(bn * 64) * HID];
    const u16* w2B = &g_W2[(bn * 64) * HID];

#define LD3(DA0, DA1, DA2, DA3, D10, D11, D12, D13, D20, D21, D22, D23, S)   \
    {                                                                        \
        int k0_ = (S) * 128;                                                 \
        DA0 = *(const u32x4*)&aB[row0 * HID + k0_ + kc0 * 8];                \
        DA1 = *(const u32x4*)&aB[row1 * HID + k0_ + kc0 * 8];                \
        DA2 = *(const u32x4*)&aB[row0 * HID + k0_ + 64 + kc0 * 8];           \
        DA3 = *(const u32x4*)&aB[row1 * HID + k0_ + 64 + kc0 * 8];           \
        D10 = *(const u32x4*)&w1B[row0 * HID + k0_ + kc0 * 8];               \
        D11 = *(const u32x4*)&w1B[row1 * HID + k0_ + kc0 * 8];               \
        D12 = *(const u32x4*)&w1B[row0 * HID + k0_ + 64 + kc0 * 8];          \
        D13 = *(const u32x4*)&w1B[row1 * HID + k0_ + 64 + kc0 * 8];          \
        D20 = *(const u32x4*)&w2B[row0 * HID + k0_ + kc0 * 8];               \
        D21 = *(const u32x4*)&w2B[row1 * HID + k0_ + kc0 * 8];               \
        D22 = *(const u32x4*)&w2B[row0 * HID + k0_ + 64 + kc0 * 8];          \
        D23 = *(const u32x4*)&w2B[row1 * HID + k0_ + 64 + kc0 * 8];          \
    }

#define FFN_COMPUTE                                                          \
    _Pragma("unroll")                                                        \
    for (int ks = 0; ks < 4; ks++) {                                         \
        s16x8 af[2], b1f[2], b2f[2];                                         \
        _Pragma("unroll")                                                    \
        for (int m = 0; m < 2; m++) {                                        \
            int row = wm * 32 + m * 16 + (l & 15);                           \
            int ch = (ks * 4 + (l >> 4)) ^ (row & 7);                        \
            af[m] = *(const s16x8*)&As[row * 128 + ch * 8];                  \
        }                                                                    \
        _Pragma("unroll")                                                    \
        for (int n = 0; n < 2; n++) {                                        \
            int col = wn * 32 + n * 16 + (l & 15);                           \
            int ch = (ks * 4 + (l >> 4)) ^ (col & 7);                        \
            b1f[n] = *(const s16x8*)&B1s[col * 128 + ch * 8];                \
            b2f[n] = *(const s16x8*)&B2s[col * 128 + ch * 8];                \
        }                                                                    \
        _Pragma("unroll")                                                    \
        for (int m = 0; m < 2; m++)                                          \
            _Pragma("unroll")                                                \
            for (int n = 0; n < 2; n++) {                                    \
                acc1[m][n] = __builtin_amdgcn_mfma_f32_16x16x32_bf16(        \
                    af[m], b1f[n], acc1[m][n], 0, 0, 0);                     \
                acc2[m][n] = __builtin_amdgcn_mfma_f32_16x16x32_bf16(        \
                    af[m], b2f[n], acc2[m][n], 0, 0, 0);                     \
            }                                                                \
    }

#define FFN_STEP(SA0, SA1, SA2, SA3, S10, S11, S12, S13, S20, S21, S22, S23, SNEXT, DOPRE) \
    {                                                                        \
        __syncthreads();                                                     \
        ((u32x4*)As)[st00] = SA0;  ((u32x4*)As)[st10] = SA1;                 \
        ((u32x4*)As)[st01] = SA2;  ((u32x4*)As)[st11] = SA3;                 \
        ((u32x4*)B1s)[st00] = S10; ((u32x4*)B1s)[st10] = S11;                \
        ((u32x4*)B1s)[st01] = S12; ((u32x4*)B1s)[st11] = S13;                \
        ((u32x4*)B2s)[st00] = S20; ((u32x4*)B2s)[st10] = S21;                \
        ((u32x4*)B2s)[st01] = S22; ((u32x4*)B2s)[st11] = S23;                \
        if (DOPRE) LD3(SA0, SA1, SA2, SA3, S10, S11, S12, S13, S20, S21, S22, S23, SNEXT); \
        __syncthreads();                                                     \
        FFN_COMPUTE;                                                         \
    }

    u32x4 xA0, xA1, xA2, xA3, p10, p11, p12, p13, p20, p21, p22, p23;  // set A
    u32x4 yA0, yA1, yA2, yA3, q10, q11, q12, q13, q20, q21, q22, q23;  // set B
    LD3(xA0, xA1, xA2, xA3, p10, p11, p12, p13, p20, p21, p22, p23, 0);
    LD3(yA0, yA1, yA2, yA3, q10, q11, q12, q13, q20, q21, q22, q23, 1);
    FFN_STEP(xA0, xA1, xA2, xA3, p10, p11, p12, p13, p20, p21, p22, p23, 2, 1);
    FFN_STEP(yA0, yA1, yA2, yA3, q10, q11, q12, q13, q20, q21, q22, q23, 3, 1);
    FFN_STEP(xA0, xA1, xA2, xA3, p10, p11, p12, p13, p20, p21, p22, p23, 0, 0);
    FFN_STEP(yA0, yA1, yA2, yA3, q10, q11, q12, q13, q20, q21, q22, q23, 0, 0);
#undef FFN_STEP
#undef FFN_COMPUTE
#undef LD3
#pragma unroll
    for (int m = 0; m < 2; m++)
#pragma unroll
        for (int n = 0; n < 2; n++)
#pragma unroll
            for (int r4 = 0; r4 < 4; r4++) {
                int row = bm * 64 + wm * 32 + m * 16 + (l >> 4) * 4 + r4;
                int col = bn * 64 + wn * 32 + n * 16 + (l & 15);
                float g1 = acc1[m][n][r4] + b1[col];
                float g2 = acc2[m][n][r4] + b2[col];
                float sg = 1.f / (1.f + __expf(-g2));
                out[row * HID + col] = x[row * HID + col] + g1 * sg;
            }
}

extern "C" void kernel_launch(void* const* d_in, const int* in_sizes, int n_in,
                              void* d_out, int out_size, void* d_ws, size_t ws_size,
                              hipStream_t stream) {
    const float* x = (const float*)d_in[0];
    const float* lre = (const float*)d_in[1];
    const float* lim = (const float*)d_in[2];
    const float* pre = (const float*)d_in[3];
    const float* pim = (const float*)d_in[4];
    const float* bre = (const float*)d_in[5];
    const float* bim = (const float*)d_in[6];
    const float* cre = (const float*)d_in[7];
    const float* cim = (const float*)d_in[8];
    const float* lstep = (const float*)d_in[9];
    const float* w1 = (const float*)d_in[10];
    const float* b1 = (const float*)d_in[11];
    const float* w2 = (const float*)d_in[12];
    const float* b2 = (const float*)d_in[13];
    float* out = (float*)d_out;

    fused_convert<<<776, 256, 0, stream>>>(x, w1, w2, lre, lim, pre, pim,
                                           bre, bim, cre, cim, lstep);
    k_build<<<32, 1024, 0, stream>>>();
    conv_gemm<<<256, 256, 0, stream>>>();
    ffn_gemm<<<256, 256, 0, stream>>>(x, b1, b2, out);
}

// Round 9
// 48.800 us; speedup vs baseline: 1.6233x; 1.6233x over previous
//
#include <hip/hip_runtime.h>
#include <hip/hip_bf16.h>

typedef unsigned short u16;
typedef short s16x8 __attribute__((ext_vector_type(8)));
typedef u16 u16x8 __attribute__((ext_vector_type(8)));
typedef unsigned int u32x4 __attribute__((ext_vector_type(4)));
typedef float f32x4 __attribute__((ext_vector_type(4)));

struct cplx { float x, y; };

#define L_SEQ 2048
#define HID 512
#define NST 64

// ---------------- device scratch (fully rewritten every call) ----------------
__device__ __align__(16) cplx g_khat[L_SEQ];        // k̂_j at 2048 roots of unity
__device__ __align__(16) float g_k[L_SEQ];
__device__ __align__(16) u16 g_Td[32 * 64 * 64];    // bf16 diagonal tiles: Td[d][r][c]=k[64d+r-c]
__device__ __align__(16) u16 g_Xt[HID * L_SEQ];     // bf16 X^T  [h][l]
__device__ __align__(16) u16 g_W1[HID * HID];       // bf16 [n][k]
__device__ __align__(16) u16 g_W2[HID * HID];
__device__ __align__(16) u16 g_H[L_SEQ * HID];      // bf16 gelu(conv out) [l][h]

__device__ __forceinline__ u16 f2bf(float f) {
    union { __hip_bfloat16 h; u16 u; } cv;
    cv.h = __float2bfloat16(f);
    return cv.u;
}

// ---------------- fused: X transpose + W converts + khat ----------------
// blocks 0..255: X -> bf16 X^T ; 256..767: W1/W2 ; 768..775: khat
// k̂_j = 2 conj(C)^T [ (2/Δ)(1-ω)I - (1+ω)A ]^{-1} B ; A = diag(Λ) - P P^H (Woodbury)
__global__ __launch_bounds__(256) void fused_convert(
    const float* x, const float* w1, const float* w2,
    const float* lre, const float* lim, const float* pre, const float* pim,
    const float* bre, const float* bim, const float* cre, const float* cim,
    const float* lstep) {
    __shared__ float tile[64][65];
    __shared__ float sLre[NST], sLim[NST], sPre[NST], sPim[NST];
    __shared__ float sBre[NST], sBim[NST], sCre[NST], sCim[NST];
    int b = blockIdx.x, tid = threadIdx.x;
    if (b < 256) {
        int lt = b >> 3, ht = b & 7;
#pragma unroll
        for (int i = 0; i < 4; i++) {
            int idx = i * 256 + tid;        // 1024 float4
            int r = idx >> 4, c4 = idx & 15;
            f32x4 v = *(const f32x4*)&x[(lt * 64 + r) * HID + ht * 64 + c4 * 4];
            tile[r][c4 * 4 + 0] = v.x;
            tile[r][c4 * 4 + 1] = v.y;
            tile[r][c4 * 4 + 2] = v.z;
            tile[r][c4 * 4 + 3] = v.w;
        }
        __syncthreads();
#pragma unroll
        for (int i = 0; i < 2; i++) {
            int idx = i * 256 + tid;        // 512 u16x8
            int rr = idx >> 3, c8 = idx & 7;
            u16x8 v;
#pragma unroll
            for (int q = 0; q < 8; q++) v[q] = f2bf(tile[c8 * 8 + q][rr]);
            *(u16x8*)&g_Xt[(ht * 64 + rr) * L_SEQ + lt * 64 + c8 * 8] = v;
        }
    } else if (b < 768) {
        int t = (b - 256) * 256 + tid;  // 131072
        const float* src = (t < 65536) ? w1 : w2;
        u16* dst = (t < 65536) ? g_W1 : g_W2;
        int idx = (t < 65536) ? t : (t - 65536);
        float4 v = ((const float4*)src)[idx];
        unsigned long long pk = (unsigned long long)f2bf(v.x) |
                                ((unsigned long long)f2bf(v.y) << 16) |
                                ((unsigned long long)f2bf(v.z) << 32) |
                                ((unsigned long long)f2bf(v.w) << 48);
        ((unsigned long long*)dst)[idx] = pk;
    } else {
        if (tid < NST) {
            sLre[tid] = lre[tid]; sLim[tid] = lim[tid];
            sPre[tid] = pre[tid]; sPim[tid] = pim[tid];
            sBre[tid] = bre[tid]; sBim[tid] = bim[tid];
            sCre[tid] = cre[tid]; sCim[tid] = cim[tid];
        }
        __syncthreads();
        int j = (b - 768) * 256 + tid;  // 0..2047
        float tdt = 2.0f * __expf(-lstep[0]);          // 2/step
        float th = 0.00306796157577128245f * j;        // 2*pi/2048 * j
        float sn, cs;
        __sincosf(th, &sn, &cs);
        float aRe = tdt * (1.f - cs), aIm = tdt * sn;  // (2/dt)(1-w)
        float bRe = 1.f + cs, bIm = -sn;               // beta = 1+w
        float cBx = 0.f, cBy = 0.f, cPx = 0.f, cPy = 0.f;
        float pBx = 0.f, pBy = 0.f, pPx = 0.f, pPy = 0.f;
#pragma unroll 8
        for (int n = 0; n < NST; n++) {
            float Lre = sLre[n], Lim = sLim[n];
            float Dre = aRe - (bRe * Lre - bIm * Lim);
            float Dim = aIm - (bRe * Lim + bIm * Lre);
            float inv = 1.f / (Dre * Dre + Dim * Dim);
            float eRe = Dre * inv, eIm = -Dim * inv;   // 1/D_n
            float cRe = sCre[n], cIm = -sCim[n];
            float t1Re = cRe * eRe - cIm * eIm, t1Im = cRe * eIm + cIm * eRe;
            float qRe = sPre[n], qIm = -sPim[n];
            float t2Re = qRe * eRe - qIm * eIm, t2Im = qRe * eIm + qIm * eRe;
            float BRe = sBre[n], BIm = sBim[n], PRe = sPre[n], PIm = sPim[n];
            cBx += t1Re * BRe - t1Im * BIm; cBy += t1Re * BIm + t1Im * BRe;
            cPx += t1Re * PRe - t1Im * PIm; cPy += t1Re * PIm + t1Im * PRe;
            pBx += t2Re * BRe - t2Im * BIm; pBy += t2Re * BIm + t2Im * BRe;
            pPx += t2Re * PRe - t2Im * PIm; pPy += t2Re * PIm + t2Im * PRe;
        }
        float denx = 1.f + (bRe * pPx - bIm * pPy);
        float deny = (bRe * pPy + bIm * pPx);
        float bcPx = bRe * cPx - bIm * cPy;
        float bcPy = bRe * cPy + bIm * cPx;
        float numx = bcPx * pBx - bcPy * pBy;
        float numy = bcPx * pBy + bcPy * pBx;
        float dinv = 1.f / (denx * denx + deny * deny);
        float corx = (numx * denx + numy * deny) * dinv;
        float cory = (numy * denx - numx * deny) * dinv;
        g_khat[j] = { 2.f * (cBx - corx), 2.f * (cBy - cory) };
    }
}

// ---------------- Re(k_t) via Hermitian-symmetrized direct IDFT ----------------
__global__ __launch_bounds__(256) void k_ifft() {
    int tid = threadIdx.x;
    int l = tid & 63;
    int t = blockIdx.x * 4 + (tid >> 6);  // 512 blocks x 4 waves = 2048 t's
    float acc = 0.f;
#pragma unroll
    for (int i = 0; i < 16; i++) {
        int j = l + 64 * i;  // 0..1023
        cplx a = g_khat[j];
        cplx b = g_khat[(2048 - j) & 2047];
        float re = 0.5f * (a.x + b.x);
        float im = 0.5f * (a.y - b.y);
        int idx = (j * t) & 2047;
        float s, c;
        __sincosf(0.00306796157577128245f * idx, &s, &c);
        float wgt = (j == 0) ? 1.f : 2.f;
        acc += wgt * (re * c - im * s);
    }
    if (l == 0) acc += (1 - 2 * (t & 1)) * g_khat[1024].x;
#pragma unroll
    for (int off = 1; off < 64; off <<= 1) acc += __shfl_xor(acc, off);
    if (l == 0) g_k[t] = acc * (1.f / 2048.f);
}

// ---------------- build 32 distinct diagonal tiles: Td[d][r][c] = k[64d + r - c] ----------------
__global__ __launch_bounds__(256) void build_Td() {
    int gid = blockIdx.x * 256 + threadIdx.x;  // 64 blocks -> 16384 threads
    int o = gid * 8;                           // 131072 elements total
    int d = o >> 12, rem = o & 4095;
    int r = rem >> 6, c0 = rem & 63;
    int base = d * 64 + r - c0;
    u16x8 v;
#pragma unroll
    for (int q = 0; q < 8; q++) {
        int idx = base - q;
        v[q] = (idx >= 0) ? f2bf(g_k[idx]) : (u16)0;
    }
    *(u16x8*)&g_Td[o] = v;
}

// ---------------- conv GEMM: Y = T @ X, BK=128, A from L2-resident Td ----------------
__global__ __launch_bounds__(256) void conv_gemm() {
    __shared__ __align__(16) u16 As[64 * 128];
    __shared__ __align__(16) u16 Bs[64 * 128];
    int tid = threadIdx.x, l = tid & 63, w = tid >> 6;
    int wm = w >> 1, wn = w & 1;
    int bm = blockIdx.x >> 3, bn = blockIdx.x & 7;  // 32 x 8
    f32x4 acc[2][2] = {};
    int nst = (bm >> 1) + 1;            // BK=128 steps (covers kb = 2s, 2s+1)
    int row0 = tid >> 3, kc0 = tid & 7;
    int row1 = row0 + 32;
    // swizzled u32x4 store slots (chunk space 16 wide, chunk = c*8 + kc)
    int st00 = row0 * 16 + ((kc0) ^ (row0 & 7));       // c=0, row0
    int st01 = row0 * 16 + ((8 + kc0) ^ (row0 & 7));   // c=1, row0
    int st10 = row1 * 16 + ((kc0) ^ (row1 & 7));
    int st11 = row1 * 16 + ((8 + kc0) ^ (row1 & 7));
    const u32x4 zz = { 0, 0, 0, 0 };

#define LOADA(D00, D10, D01, D11, S)                                         \
    {                                                                        \
        int d0_ = bm - 2 * (S), d1_ = d0_ - 1;                               \
        if (d0_ >= 0) {                                                      \
            D00 = *(const u32x4*)&g_Td[d0_ * 4096 + row0 * 64 + kc0 * 8];    \
            D10 = *(const u32x4*)&g_Td[d0_ * 4096 + row1 * 64 + kc0 * 8];    \
        } else { D00 = zz; D10 = zz; }                                       \
        if (d1_ >= 0) {                                                      \
            D01 = *(const u32x4*)&g_Td[d1_ * 4096 + row0 * 64 + kc0 * 8];    \
            D11 = *(const u32x4*)&g_Td[d1_ * 4096 + row1 * 64 + kc0 * 8];    \
        } else { D01 = zz; D11 = zz; }                                       \
    }
#define LOADB(D00, D10, D01, D11, S)                                         \
    {                                                                        \
        int k0_ = (S) * 128;                                                 \
        D00 = *(const u32x4*)&g_Xt[(bn * 64 + row0) * L_SEQ + k0_ + kc0 * 8];        \
        D10 = *(const u32x4*)&g_Xt[(bn * 64 + row1) * L_SEQ + k0_ + kc0 * 8];        \
        D01 = *(const u32x4*)&g_Xt[(bn * 64 + row0) * L_SEQ + k0_ + 64 + kc0 * 8];   \
        D11 = *(const u32x4*)&g_Xt[(bn * 64 + row1) * L_SEQ + k0_ + 64 + kc0 * 8];   \
    }

#define CONV_COMPUTE                                                         \
    _Pragma("unroll")                                                        \
    for (int ks = 0; ks < 4; ks++) {                                         \
        s16x8 af[2], bf[2];                                                  \
        _Pragma("unroll")                                                    \
        for (int m = 0; m < 2; m++) {                                        \
            int row = wm * 32 + m * 16 + (l & 15);                           \
            int ch = (ks * 4 + (l >> 4)) ^ (row & 7);                        \
            af[m] = *(const s16x8*)&As[row * 128 + ch * 8];                  \
        }                                                                    \
        _Pragma("unroll")                                                    \
        for (int n = 0; n < 2; n++) {                                        \
            int col = wn * 32 + n * 16 + (l & 15);                           \
            int ch = (ks * 4 + (l >> 4)) ^ (col & 7);                        \
            bf[n] = *(const s16x8*)&Bs[col * 128 + ch * 8];                  \
        }                                                                    \
        _Pragma("unroll")                                                    \
        for (int m = 0; m < 2; m++)                                          \
            _Pragma("unroll")                                                \
            for (int n = 0; n < 2; n++)                                      \
                acc[m][n] = __builtin_amdgcn_mfma_f32_16x16x32_bf16(         \
                    af[m], bf[n], acc[m][n], 0, 0, 0);                       \
    }

#define CONV_STEP(A00, A10, A01, A11, B00, B10, B01, B11)                    \
    {                                                                        \
        __syncthreads();                                                     \
        ((u32x4*)As)[st00] = A00; ((u32x4*)As)[st10] = A10;                  \
        ((u32x4*)As)[st01] = A01; ((u32x4*)As)[st11] = A11;                  \
        ((u32x4*)Bs)[st00] = B00; ((u32x4*)Bs)[st10] = B10;                  \
        ((u32x4*)Bs)[st01] = B01; ((u32x4*)Bs)[st11] = B11;                  \
        if (s + 2 < nst) {                                                   \
            LOADA(A00, A10, A01, A11, s + 2);                                \
            LOADB(B00, B10, B01, B11, s + 2);                                \
        }                                                                    \
        __syncthreads();                                                     \
        CONV_COMPUTE;                                                        \
        s++;                                                                 \
    }

    u32x4 aA00, aA10, aA01, aA11, bA00, bA10, bA01, bA11;
    u32x4 aB00, aB10, aB01, aB11, bB00, bB10, bB01, bB11;
    LOADA(aA00, aA10, aA01, aA11, 0);
    LOADB(bA00, bA10, bA01, bA11, 0);
    int sp = (nst > 1) ? 1 : 0;
    LOADA(aB00, aB10, aB01, aB11, sp);
    LOADB(bB00, bB10, bB01, bB11, sp);
    int s = 0;
    while (true) {
        CONV_STEP(aA00, aA10, aA01, aA11, bA00, bA10, bA01, bA11);
        if (s >= nst) break;
        CONV_STEP(aB00, aB10, aB01, aB11, bB00, bB10, bB01, bB11);
        if (s >= nst) break;
    }
#undef CONV_STEP
#undef CONV_COMPUTE
#undef LOADA
#undef LOADB
#pragma unroll
    for (int m = 0; m < 2; m++)
#pragma unroll
        for (int n = 0; n < 2; n++)
#pragma unroll
            for (int r4 = 0; r4 < 4; r4++) {
                int row = bm * 64 + wm * 32 + m * 16 + (l >> 4) * 4 + r4;
                int col = bn * 64 + wn * 32 + n * 16 + (l & 15);
                float y = acc[m][n][r4];
                float u = 1.5957691216057308f * (y + 0.044715f * y * y * y);
                float th = 1.f - 2.f / (__expf(u) + 1.f);
                g_H[row * HID + col] = f2bf(0.5f * y * (1.f + th));
            }
}

// ---------------- FFN: out = x + (H@W1^T + b1) * sigmoid(H@W2^T + b2), BK=128 ----------------
__global__ __launch_bounds__(256) void ffn_gemm(const float* x, const float* b1,
                                                const float* b2, float* out) {
    __shared__ __align__(16) u16 As[64 * 128];
    __shared__ __align__(16) u16 B1s[64 * 128];
    __shared__ __align__(16) u16 B2s[64 * 128];
    int tid = threadIdx.x, l = tid & 63, w = tid >> 6;
    int wm = w >> 1, wn = w & 1;
    int bm = blockIdx.x >> 3, bn = blockIdx.x & 7;  // 32 x 8
    f32x4 acc1[2][2] = {}, acc2[2][2] = {};
    int row0 = tid >> 3, kc0 = tid & 7;
    int row1 = row0 + 32;
    int st00 = row0 * 16 + ((kc0) ^ (row0 & 7));
    int st01 = row0 * 16 + ((8 + kc0) ^ (row0 & 7));
    int st10 = row1 * 16 + ((kc0) ^ (row1 & 7));
    int st11 = row1 * 16 + ((8 + kc0) ^ (row1 & 7));
    const u16* aB = &g_H[(bm * 64) * HID];
    const u16* w1B = &g_W1[(bn * 64) * HID];
    const u16* w2B = &g_W2[(bn * 64) * HID];

#define LD3(DA0, DA1, DA2, DA3, D10, D11, D12, D13, D20, D21, D22, D23, S)   \
    {                                                                        \
        int k0_ = (S) * 128;                                                 \
        DA0 = *(const u32x4*)&aB[row0 * HID + k0_ + kc0 * 8];                \
        DA1 = *(const u32x4*)&aB[row1 * HID + k0_ + kc0 * 8];                \
        DA2 = *(const u32x4*)&aB[row0 * HID + k0_ + 64 + kc0 * 8];           \
        DA3 = *(const u32x4*)&aB[row1 * HID + k0_ + 64 + kc0 * 8];           \
        D10 = *(const u32x4*)&w1B[row0 * HID + k0_ + kc0 * 8];               \
        D11 = *(const u32x4*)&w1B[row1 * HID + k0_ + kc0 * 8];               \
        D12 = *(const u32x4*)&w1B[row0 * HID + k0_ + 64 + kc0 * 8];          \
        D13 = *(const u32x4*)&w1B[row1 * HID + k0_ + 64 + kc0 * 8];          \
        D20 = *(const u32x4*)&w2B[row0 * HID + k0_ + kc0 * 8];               \
        D21 = *(const u32x4*)&w2B[row1 * HID + k0_ + kc0 * 8];               \
        D22 = *(const u32x4*)&w2B[row0 * HID + k0_ + 64 + kc0 * 8];          \
        D23 = *(const u32x4*)&w2B[row1 * HID + k0_ + 64 + kc0 * 8];          \
    }

#define FFN_COMPUTE                                                          \
    _Pragma("unroll")                                                        \
    for (int ks = 0; ks < 4; ks++) {                                         \
        s16x8 af[2], b1f[2], b2f[2];                                         \
        _Pragma("unroll")                                                    \
        for (int m = 0; m < 2; m++) {                                        \
            int row = wm * 32 + m * 16 + (l & 15);                           \
            int ch = (ks * 4 + (l >> 4)) ^ (row & 7);                        \
            af[m] = *(const s16x8*)&As[row * 128 + ch * 8];                  \
        }                                                                    \
        _Pragma("unroll")                                                    \
        for (int n = 0; n < 2; n++) {                                        \
            int col = wn * 32 + n * 16 + (l & 15);                           \
            int ch = (ks * 4 + (l >> 4)) ^ (col & 7);                        \
            b1f[n] = *(const s16x8*)&B1s[col * 128 + ch * 8];                \
            b2f[n] = *(const s16x8*)&B2s[col * 128 + ch * 8];                \
        }                                                                    \
        _Pragma("unroll")                                                    \
        for (int m = 0; m < 2; m++)                                          \
            _Pragma("unroll")                                                \
            for (int n = 0; n < 2; n++) {                                    \
                acc1[m][n] = __builtin_amdgcn_mfma_f32_16x16x32_bf16(        \
                    af[m], b1f[n], acc1[m][n], 0, 0, 0);                     \
                acc2[m][n] = __builtin_amdgcn_mfma_f32_16x16x32_bf16(        \
                    af[m], b2f[n], acc2[m][n], 0, 0, 0);                     \
            }                                                                \
    }

#define FFN_STEP(SA0, SA1, SA2, SA3, S10, S11, S12, S13, S20, S21, S22, S23, SNEXT, DOPRE) \
    {                                                                        \
        __syncthreads();                                                     \
        ((u32x4*)As)[st00] = SA0;  ((u32x4*)As)[st10] = SA1;                 \
        ((u32x4*)As)[st01] = SA2;  ((u32x4*)As)[st11] = SA3;                 \
        ((u32x4*)B1s)[st00] = S10; ((u32x4*)B1s)[st10] = S11;                \
        ((u32x4*)B1s)[st01] = S12; ((u32x4*)B1s)[st11] = S13;                \
        ((u32x4*)B2s)[st00] = S20; ((u32x4*)B2s)[st10] = S21;                \
        ((u32x4*)B2s)[st01] = S22; ((u32x4*)B2s)[st11] = S23;                \
        if (DOPRE) LD3(SA0, SA1, SA2, SA3, S10, S11, S12, S13, S20, S21, S22, S23, SNEXT); \
        __syncthreads();                                                     \
        FFN_COMPUTE;                                                         \
    }

    u32x4 xA0, xA1, xA2, xA3, p10, p11, p12, p13, p20, p21, p22, p23;  // set A
    u32x4 yA0, yA1, yA2, yA3, q10, q11, q12, q13, q20, q21, q22, q23;  // set B
    LD3(xA0, xA1, xA2, xA3, p10, p11, p12, p13, p20, p21, p22, p23, 0);
    LD3(yA0, yA1, yA2, yA3, q10, q11, q12, q13, q20, q21, q22, q23, 1);
    FFN_STEP(xA0, xA1, xA2, xA3, p10, p11, p12, p13, p20, p21, p22, p23, 2, 1);
    FFN_STEP(yA0, yA1, yA2, yA3, q10, q11, q12, q13, q20, q21, q22, q23, 3, 1);
    FFN_STEP(xA0, xA1, xA2, xA3, p10, p11, p12, p13, p20, p21, p22, p23, 0, 0);
    FFN_STEP(yA0, yA1, yA2, yA3, q10, q11, q12, q13, q20, q21, q22, q23, 0, 0);
#undef FFN_STEP
#undef FFN_COMPUTE
#undef LD3
#pragma unroll
    for (int m = 0; m < 2; m++)
#pragma unroll
        for (int n = 0; n < 2; n++)
#pragma unroll
            for (int r4 = 0; r4 < 4; r4++) {
                int row = bm * 64 + wm * 32 + m * 16 + (l >> 4) * 4 + r4;
                int col = bn * 64 + wn * 32 + n * 16 + (l & 15);
                float g1 = acc1[m][n][r4] + b1[col];
                float g2 = acc2[m][n][r4] + b2[col];
                float sg = 1.f / (1.f + __expf(-g2));
                out[row * HID + col] = x[row * HID + col] + g1 * sg;
            }
}

extern "C" void kernel_launch(void* const* d_in, const int* in_sizes, int n_in,
                              void* d_out, int out_size, void* d_ws, size_t ws_size,
                              hipStream_t stream) {
    const float* x = (const float*)d_in[0];
    const float* lre = (const float*)d_in[1];
    const float* lim = (const float*)d_in[2];
    const float* pre = (const float*)d_in[3];
    const float* pim = (const float*)d_in[4];
    const float* bre = (const float*)d_in[5];
    const float* bim = (const float*)d_in[6];
    const float* cre = (const float*)d_in[7];
    const float* cim = (const float*)d_in[8];
    const float* lstep = (const float*)d_in[9];
    const float* w1 = (const float*)d_in[10];
    const float* b1 = (const float*)d_in[11];
    const float* w2 = (const float*)d_in[12];
    const float* b2 = (const float*)d_in[13];
    float* out = (float*)d_out;

    fused_convert<<<776, 256, 0, stream>>>(x, w1, w2, lre, lim, pre, pim,
                                           bre, bim, cre, cim, lstep);
    k_ifft<<<512, 256, 0, stream>>>();
    build_Td<<<64, 256, 0, stream>>>();
    conv_gemm<<<256, 256, 0, stream>>>();
    ffn_gemm<<<256, 256, 0, stream>>>(x, b1, b2, out);
}